// Round 1
// baseline (322.220 us; speedup 1.0000x reference)
//
#include <hip/hip_runtime.h>

#define N_NODES 100000
#define N_EDGES 1600000
#define F_DIM 48

// Zero-init the output buffer (harness re-poisons d_out with 0xAA before
// every timed launch, so we must clear it ourselves on every call).
__global__ void zero_out_kernel(float4* __restrict__ out, int n_vec4) {
    int i = blockIdx.x * blockDim.x + threadIdx.x;
    if (i < n_vec4) {
        out[i] = make_float4(0.f, 0.f, 0.f, 0.f);
    }
}

// Fused scatter: out[row[e], f] += val[e] * x[col[e], f] * w[f]
// 16 lanes per edge; lane l owns features {l, l+16, l+32} so each 16-lane
// group issues coalesced 64B gathers from x and coalesced atomics to out.
__global__ void scatter_kernel(const float* __restrict__ x,
                               const float* __restrict__ w,
                               const int* __restrict__ rows,
                               const int* __restrict__ cols,
                               const float* __restrict__ vals,
                               float* __restrict__ out) {
    int tid = blockIdx.x * blockDim.x + threadIdx.x;
    int edge = tid >> 4;
    int l = tid & 15;
    if (edge >= N_EDGES) return;

    int col = cols[edge];
    int row = rows[edge];
    float val = vals[edge];

    const float* __restrict__ xr = x + (size_t)col * F_DIM;
    float* __restrict__ orow = out + (size_t)row * F_DIM;

#pragma unroll
    for (int k = 0; k < 3; ++k) {
        int f = l + k * 16;
        atomicAdd(&orow[f], val * xr[f] * w[f]);
    }
}

extern "C" void kernel_launch(void* const* d_in, const int* in_sizes, int n_in,
                              void* d_out, int out_size, void* d_ws, size_t ws_size,
                              hipStream_t stream) {
    const float* x    = (const float*)d_in[0];  // [1, N_NODES, F_DIM] f32
    const float* w    = (const float*)d_in[1];  // [1, F_DIM] f32
    const int*   rows = (const int*)d_in[2];    // [N_EDGES] i32
    const int*   cols = (const int*)d_in[3];    // [N_EDGES] i32
    const float* vals = (const float*)d_in[4];  // [N_EDGES] f32
    float* out = (float*)d_out;                 // [N_NODES, F_DIM] f32

    // 1) zero the output
    int n_vec4 = (N_NODES * F_DIM) / 4;  // 1.2M float4, F_DIM=48 divisible by 4
    int zb = 256;
    int zg = (n_vec4 + zb - 1) / zb;
    zero_out_kernel<<<zg, zb, 0, stream>>>((float4*)out, n_vec4);

    // 2) fused scatter-accumulate with weight scaling
    int total_threads = N_EDGES * 16;
    int sb = 256;
    int sg = (total_threads + sb - 1) / sb;
    scatter_kernel<<<sg, sb, 0, stream>>>(x, w, rows, cols, vals, out);
}